// Round 3
// baseline (801.581 us; speedup 1.0000x reference)
//
#include <hip/hip_runtime.h>
#include <math.h>

// Problem constants (fixed by the reference)
#define BN 256     // batch N
#define TT 1000    // timesteps
#define NO 10      // obs dim
#define NS 10      // state dim
#define HID 64     // GRU hidden
#define DIN 20     // NO + NS
#define G3 192     // 3*HID
#define WV 4       // waves per sample (k-split)
#define KW 16      // HID / WV
#define GS 8       // steps per group (1000 = 125 * 8)
#define NG 125     // groups
#define SPB 2      // samples per block (R8: latency-hiding pairing)

// broadcast lane `l`'s value of v to all lanes (l wave-uniform)
__device__ __forceinline__ float bcast(float v, int l) {
    return __int_as_float(__builtin_amdgcn_readlane(__float_as_int(v), l));
}
__device__ __forceinline__ float rcpf(float x) { return __builtin_amdgcn_rcpf(x); }

// Workgroup barrier WITHOUT the vmcnt(0) drain __syncthreads() emits.
__device__ __forceinline__ void sync_lds() {
    asm volatile("s_waitcnt lgkmcnt(0)\n\ts_barrier" ::: "memory");
}

// ---------------- Phase 1: GRU recurrence ----------------------------------
// R8: measured cost surface across k-split configs (R5/R6/R7):
//   4-wave 1240 cy/step | 2-wave 1594 | 1-wave 2312 (reg overflow)
// Per-wave issue grows with KW; the ~600 cy of sync latency (ds_write ->
// barrier -> ds_read -> nonlin tail) is FIXED, and with 1 wave/SIMD it is
// pure idle time (VALUBusy 50%). Fix: TWO independent samples per block
// (8 waves = two 4-wave groups, 2 waves/SIMD). While group A sits in its
// LDS round-trip, group B issues. Shared s_barrier lockstesps the rhythm
// but the issue bursts interleave -> issue-bound, ~650 cy/step/sample.
// waves_per_eu(2,2): 256-VGPR budget/wave (kernel needs ~132).
__global__
__attribute__((amdgpu_flat_work_group_size(512, 512), amdgpu_waves_per_eu(2, 2)))
void gru_phase1(const float* __restrict__ Yi, const float* __restrict__ Xh,
                const float* __restrict__ Wi, const float* __restrict__ Wh,
                const float* __restrict__ bi, const float* __restrict__ bh,
                const float* __restrict__ Wmu, const float* __restrict__ Wvar,
                float* __restrict__ mv_out) {
    const int tid  = threadIdx.x;
    const int grp  = tid >> 8;        // sample group 0..1
    const int tidg = tid & 255;       // thread id within group
    const int lane = tidg & 63;       // hidden unit index
    const int w = tidg >> 6;          // wave id within group 0..3
    const int kb = w * KW;            // k-range base (hidden)

    // packed partials: [grp][buf][wave][lane] = {r, z, nx, nh}  (16 KB)
    __shared__ float4 part[SPB][2][WV][HID];
    // amv partials (separate, reduced by wave 3 only)            (4 KB)
    __shared__ float pamv[SPB][2][WV][HID];
    // input staging: per group-of-8-steps 160 floats = [y(8x10) | x(8x10)]
    __shared__ float inbuf[SPB][2][GS * DIN];
    // output staging: per group 160 floats = [step][20]
    __shared__ float obuf[SPB][2][GS * DIN];

    const int n = blockIdx.x * SPB + grp;
    const float* ybase = Yi + (size_t)n * TT * NO;
    const float* xbase = Xh + (size_t)n * TT * NS;
    float* obase = mv_out + (size_t)n * TT * DIN;

    // ---- per-lane weight slices (all register-resident) ----
    float whr[KW], whz[KW], whn[KW], wmv[KW];
#pragma unroll
    for (int k = 0; k < KW; ++k) {
        const int kk = kb + k;
        whr[k] = Wh[kk * G3 + lane];
        whz[k] = Wh[kk * G3 + 64 + lane];
        whn[k] = Wh[kk * G3 + 128 + lane];
        float wm = (lane < NS) ? Wmu[kk * NS + lane] : 0.0f;
        float wv = (lane >= NS && lane < 2 * NS) ? Wvar[kk * NS + (lane - NS)] : 0.0f;
        wmv[k] = wm + wv;   // packed: lanes 0..9 -> W_mu, lanes 10..19 -> W_var
    }
    float wir[5], wiz[5], win[5];
#pragma unroll
    for (int k = 0; k < 5; ++k) {
        const int d = 5 * w + k;    // this wave's input dims
        wir[k] = Wi[d * G3 + lane];
        wiz[k] = Wi[d * G3 + 64 + lane];
        win[k] = Wi[d * G3 + 128 + lane];
    }
    const float b_r  = bi[lane] + bh[lane];
    const float b_z  = bi[64 + lane] + bh[64 + lane];
    const float bx_n = bi[128 + lane];
    const float bh_n = bh[128 + lane];

    // LDS offset of this wave's 5 input dims within a step row
    const int ibase = ((w >= 2) ? 80 : 0) + (w & 1) * 5;

    // prologue: stage group 0
    if (tidg < 160)
        inbuf[grp][0][tidg] = (tidg < 80) ? ybase[tidg] : xbase[tidg - 80];
    sync_lds();

    float h = 0.0f;

#pragma unroll 1
    for (int g = 0; g < NG; ++g) {
        // next group's coalesced load; stays in flight across the barriers
        float ld = 0.0f;
        const bool do_ld = (tidg < 160) && (g + 1 < NG);
        if (do_ld)
            ld = (tidg < 80) ? ybase[(size_t)(g + 1) * 80 + tidg]
                             : xbase[(size_t)(g + 1) * 80 + (tidg - 80)];
        const float* ib = inbuf[grp][g & 1];

#pragma unroll
        for (int s = 0; s < GS; ++s) {
            // ---- pre-barrier: partial sums from h (= h_{t-1}, t = 8g+s) ----
            const int ro = ibase + 10 * s;
            const float x0 = ib[ro], x1 = ib[ro + 1], x2 = ib[ro + 2];
            const float x3 = ib[ro + 3], x4 = ib[ro + 4];
            float pr = x0 * wir[0], pz = x0 * wiz[0], px = x0 * win[0];
            pr = fmaf(x1, wir[1], pr); pz = fmaf(x1, wiz[1], pz); px = fmaf(x1, win[1], px);
            pr = fmaf(x2, wir[2], pr); pz = fmaf(x2, wiz[2], pz); px = fmaf(x2, win[2], px);
            pr = fmaf(x3, wir[3], pr); pz = fmaf(x3, wiz[3], pz); px = fmaf(x3, win[3], px);
            pr = fmaf(x4, wir[4], pr); pz = fmaf(x4, wiz[4], pz); px = fmaf(x4, win[4], px);
            float pn = 0.0f, pm = 0.0f;
#pragma unroll
            for (int k = 0; k < KW; ++k) {
                float sv = bcast(h, kb + k);
                pr = fmaf(sv, whr[k], pr);
                pz = fmaf(sv, whz[k], pz);
                pn = fmaf(sv, whn[k], pn);
                pm = fmaf(sv, wmv[k], pm);
            }
            const int bufp = s & 1;
            part[grp][bufp][w][lane] = make_float4(pr, pz, px, pn);  // ds_write_b128
            pamv[grp][bufp][w][lane] = pm;
            // stage next group's inputs just before the group's last barrier
            if (s == GS - 1 && do_ld) inbuf[grp][(g + 1) & 1][tidg] = ld;
            sync_lds();

            // ---- post-barrier: reduce (4x ds_read_b128) + nonlinearity ----
            const float4 q0 = part[grp][bufp][0][lane];
            const float4 q1 = part[grp][bufp][1][lane];
            const float4 q2 = part[grp][bufp][2][lane];
            const float4 q3 = part[grp][bufp][3][lane];
            const float ar = b_r  + ((q0.x + q1.x) + (q2.x + q3.x));
            const float az = b_z  + ((q0.y + q1.y) + (q2.y + q3.y));
            const float ax = bx_n + ((q0.z + q1.z) + (q2.z + q3.z));
            const float ah = bh_n + ((q0.w + q1.w) + (q2.w + q3.w));
            if (w == 3) {   // amv for output t-1
                float amv = (pamv[grp][bufp][0][lane] + pamv[grp][bufp][1][lane])
                          + (pamv[grp][bufp][2][lane] + pamv[grp][bufp][3][lane]);
                if (lane < DIN && !(g == 0 && s == 0)) {
                    const int tm1 = 8 * g + s - 1;
                    obuf[grp][(tm1 >> 3) & 1][(tm1 & 7) * DIN + lane] = amv;
                }
            }
            // flush previous output group (slot 7 stashed post-s==0-barrier,
            // ordered by the s==1 barrier); store stays in flight (no vmcnt)
            if (s == 1 && g >= 1 && tidg < 160)
                obase[(size_t)(g - 1) * 160 + tidg] = obuf[grp][(g - 1) & 1][tidg];

            float r = rcpf(1.0f + __expf(-ar));
            float z = rcpf(1.0f + __expf(-az));
            float pre = fmaf(r, ah, ax);
            float e2 = __expf(2.0f * pre);       // inf-safe: nn -> +/-1
            float nn = 1.0f - 2.0f * rcpf(e2 + 1.0f);
            h = fmaf(z, h - nn, nn);             // (1-z)*n + z*h
        }
    }

    // epilogue: output 999 from h_999, then flush output group 124
    {
        float pm = 0.0f;
#pragma unroll
        for (int k = 0; k < KW; ++k) pm = fmaf(bcast(h, kb + k), wmv[k], pm);
        pamv[grp][0][w][lane] = pm;   // buf 0: last read was t=998 (pre-s7 barrier)
        sync_lds();
        if (w == 3 && lane < DIN) {
            float amv = (pamv[grp][0][0][lane] + pamv[grp][0][1][lane])
                      + (pamv[grp][0][2][lane] + pamv[grp][0][3][lane]);
            obuf[grp][0][7 * DIN + lane] = amv;  // t=999: group 124, slot 7, buf 0
        }
        sync_lds();
        if (tidg < 160)
            obase[(size_t)(NG - 1) * 160 + tidg] = obuf[grp][0][tidg];
    }
}

// ---------------- d_out init: the constant term ----------------------------
__global__ void init_out(float* out) {
    // -0.5*NO*T*log(2pi) / (T*NO) = -0.5*log(2pi)
    out[0] = -0.918938533204672742f;
}

// ---------------- Phase 2: per-(n,t) Gaussian log-lik ----------------------
__global__ __launch_bounds__(256)
void lik_phase2(const float* __restrict__ Yi, const float* __restrict__ Cw,
                const float* __restrict__ Hm, const float* __restrict__ mu_w,
                const float* __restrict__ b_mu, const float* __restrict__ b_var,
                const float* __restrict__ mv_in, float* __restrict__ out) {
    __shared__ float sH[NO * NS];
    __shared__ float smw[NO], sbm[NS], sbv[NS];
    __shared__ float ssum[4];
    const int tid = threadIdx.x;
    if (tid < NO * NS) sH[tid] = Hm[tid];
    if (tid < NO) smw[tid] = mu_w[tid];
    if (tid < NS) { sbm[tid] = b_mu[tid]; sbv[tid] = b_var[tid]; }
    __syncthreads();

    const int gid = blockIdx.x * 256 + tid;   // 0 .. BN*TT-1
    float contrib = 0.0f;
    if (gid < BN * TT) {
        const int n = gid / TT;
        const float* mv = mv_in + (size_t)gid * DIN;
        float mu[NS], va[NS];
#pragma unroll
        for (int i = 0; i < NS; ++i) {
            mu[i] = mv[i] + sbm[i];
            float x = mv[NS + i] + sbv[i];
            va[i] = (x > 0.0f) ? (x + log1pf(__expf(-x))) : log1pf(__expf(x));
        }
        const float* y = Yi + (size_t)gid * NO;
        float e[NO];
#pragma unroll
        for (int i = 0; i < NO; ++i) {
            float m = smw[i];
#pragma unroll
            for (int j = 0; j < NS; ++j) m = fmaf(sH[i * NS + j], mu[j], m);
            e[i] = y[i] - m;
        }
        // M = H diag(va) H^T + Cw (lower triangle only)
        float M[NO][NO];
        const float* cw = Cw + (size_t)n * NO * NO;
#pragma unroll
        for (int i = 0; i < NO; ++i)
#pragma unroll
            for (int j = 0; j <= i; ++j) M[i][j] = cw[i * NO + j];
#pragma unroll
        for (int l = 0; l < NS; ++l) {
            float vl = va[l];
            float hv[NO];
#pragma unroll
            for (int i = 0; i < NO; ++i) hv[i] = sH[i * NS + l];
#pragma unroll
            for (int i = 0; i < NO; ++i) {
                float hvi = hv[i] * vl;
#pragma unroll
                for (int j = 0; j <= i; ++j) M[i][j] = fmaf(hvi, hv[j], M[i][j]);
            }
        }
        // in-place Cholesky (lower); fast rsqrt/rcp (error ~1ulp, harmless
        // vs the 3.1e-2 threshold on an averaged scalar)
        float logdet = 0.0f;
        float drs[NO];                  // 1/sqrt(d_j) for the forward solve
#pragma unroll
        for (int j = 0; j < NO; ++j) {
            float d = M[j][j];
#pragma unroll
            for (int k = 0; k < j; ++k) d = fmaf(-M[j][k], M[j][k], d);
            logdet += __logf(d);
            float rs = __frsqrt_rn(d);
            drs[j] = rs;
            M[j][j] = d * rs;           // sqrt(d)
#pragma unroll
            for (int i = j + 1; i < NO; ++i) {
                float v = M[i][j];
#pragma unroll
                for (int k = 0; k < j; ++k) v = fmaf(-M[i][k], M[j][k], v);
                M[i][j] = v * rs;
            }
        }
        // quad = || L^-1 e ||^2 (forward solve)
        float wv[NO];
        float quad = 0.0f;
#pragma unroll
        for (int i = 0; i < NO; ++i) {
            float v = e[i];
#pragma unroll
            for (int k = 0; k < i; ++k) v = fmaf(-M[i][k], wv[k], v);
            wv[i] = v * drs[i] * rcpf(M[i][i] * drs[i]);  // v / M[i][i]
            quad = fmaf(wv[i], wv[i], quad);
        }
        const float SCALE = 0.5f / ((float)BN * (float)TT * (float)NO);
        contrib = -(logdet + quad) * SCALE;
    }

    // block reduction: wave shuffle, LDS across 4 waves, one atomic
#pragma unroll
    for (int off = 32; off > 0; off >>= 1) contrib += __shfl_down(contrib, off);
    if ((tid & 63) == 0) ssum[tid >> 6] = contrib;
    __syncthreads();
    if (tid == 0) {
        float s = ssum[0] + ssum[1] + ssum[2] + ssum[3];
        atomicAdd(out, s);
    }
}

// ---------------- launch ---------------------------------------------------
extern "C" void kernel_launch(void* const* d_in, const int* in_sizes, int n_in,
                              void* d_out, int out_size, void* d_ws, size_t ws_size,
                              hipStream_t stream) {
    const float* Yi    = (const float*)d_in[0];
    const float* Xh    = (const float*)d_in[1];
    const float* Cw    = (const float*)d_in[2];
    const float* Hm    = (const float*)d_in[3];
    const float* mu_w  = (const float*)d_in[4];
    const float* Wi    = (const float*)d_in[5];
    const float* Wh    = (const float*)d_in[6];
    const float* bi    = (const float*)d_in[7];
    const float* bh    = (const float*)d_in[8];
    const float* W_mu  = (const float*)d_in[9];
    const float* b_mu  = (const float*)d_in[10];
    const float* W_var = (const float*)d_in[11];
    const float* b_var = (const float*)d_in[12];
    float* out = (float*)d_out;
    float* mv  = (float*)d_ws;   // [BN*TT*DIN] floats = 20.48 MB

    init_out<<<1, 1, 0, stream>>>(out);
    gru_phase1<<<dim3(BN / SPB), dim3(512), 0, stream>>>(Yi, Xh, Wi, Wh, bi, bh,
                                                         W_mu, W_var, mv);
    lik_phase2<<<dim3((BN * TT + 255) / 256), dim3(256), 0, stream>>>(
        Yi, Cw, Hm, mu_w, b_mu, b_var, mv, out);
}

// Round 5
// 706.732 us; speedup vs baseline: 1.1342x; 1.1342x over previous
//
#include <hip/hip_runtime.h>
#include <math.h>

// Problem constants (fixed by the reference)
#define BN 256     // batch N
#define TT 1000    // timesteps
#define NO 10      // obs dim
#define NS 10      // state dim
#define HID 64     // GRU hidden
#define DIN 20     // NO + NS
#define G3 192     // 3*HID
#define GS 8       // steps per staged input group (1000 = 125*8)
#define NG 125     // groups
#define SPW 16     // samples per block (MFMA M dimension)
#define NBLK (BN / SPW)   // 16 blocks

using bf16x8 = __attribute__((ext_vector_type(8))) short;
using f32x4  = __attribute__((ext_vector_type(4))) float;

__device__ __forceinline__ float rcpf(float x) { return __builtin_amdgcn_rcpf(x); }
// workgroup barrier without the vmcnt(0) drain __syncthreads() emits
__device__ __forceinline__ void sync_lds() {
    asm volatile("s_waitcnt lgkmcnt(0)\n\ts_barrier" ::: "memory");
}
__device__ __forceinline__ unsigned cvt_pk_bf16(float a, float b) {   // lo<-a, hi<-b
    unsigned r;
    asm("v_cvt_pk_bf16_f32 %0, %1, %2" : "=v"(r) : "v"(a), "v"(b));
    return r;
}
__device__ __forceinline__ short f2bf(float f) {   // RNE f32->bf16 (init path only)
    unsigned u = __float_as_uint(f);
    return (short)((u + 0x7fffu + ((u >> 16) & 1u)) >> 16);
}
#define MFMA16 __builtin_amdgcn_mfma_f32_16x16x32_bf16

// Stage one (sample, step, half) row: 16 bf16 slots, PADS WRITTEN AS ZERO.
// R4 NaN root cause: pad slots 5-7/13-15 were never initialized; LDS garbage
// can be bf16 Inf/NaN and MFMA computes 0*Inf = NaN. Two b128 writes cover
// all 16 slots deterministically every group.
__device__ __forceinline__ void stage16(ushort* wp, float2 L0, float2 L1,
                                        float2 L2, float2 L3, float2 L4) {
    uint4 a, b;
    a.x = cvt_pk_bf16(L0.x, L0.y);   // slots 0,1 = dims 0,1
    a.y = cvt_pk_bf16(L1.x, L1.y);   // slots 2,3 = dims 2,3
    a.z = cvt_pk_bf16(L2.x, 0.f);    // slot 4 = dim 4, slot 5 = 0
    a.w = 0u;                        // slots 6,7 = 0
    b.x = cvt_pk_bf16(L2.y, L3.x);   // slots 8,9 = dims 5,6
    b.y = cvt_pk_bf16(L3.y, L4.x);   // slots 10,11 = dims 7,8
    b.z = cvt_pk_bf16(L4.y, 0.f);    // slot 12 = dim 9, slot 13 = 0
    b.w = 0u;                        // slots 14,15 = 0
    *(uint4*)(wp)     = a;           // 16B-aligned: row base is 32B-aligned
    *(uint4*)(wp + 8) = b;
}

// ---------------- Phase 1: GRU via MFMA, 16 samples per block --------------
// R9: R0-R8 mapped the scalar-FMA cost surface: 4-wave k-split is its optimum
// (1240 cy/step/sample = 620 issue + 620 sync) and with batch == CU count
// there is no spare parallelism to hide the stall. MFMA changes the work
// itself: A = [16 samples x K] (h_{t-1}, x_t in bf16), B = weight columns
// (bf16, register-resident, built once), D = [16 samples x 16 cols] f32.
// Wave w owns units 16w..16w+16: tiles r/z/nx/nh (+ mv for waves 0,1).
// K-map risk cancels: any k-bijection works as long as B mirrors A's map
// (both built here). D-layout is the HW-verified col=lane&15,
// row=(lane>>4)*4+reg. Only MFMA inputs are bf16; h/gates/accum stay f32.
__global__ __launch_bounds__(256)
void gru_mfma(const float* __restrict__ Yi, const float* __restrict__ Xh,
              const float* __restrict__ Wi, const float* __restrict__ Wh,
              const float* __restrict__ bi, const float* __restrict__ bh,
              const float* __restrict__ Wmu, const float* __restrict__ Wvar,
              float* __restrict__ mv_out) {
    const int tid = threadIdx.x;
    const int lane = tid & 63;
    const int w   = tid >> 6;      // wave 0..3, owns units 16w..16w+16
    const int l15 = lane & 15;
    const int lg  = lane >> 4;     // lane group 0..3
    const int n0  = blockIdx.x * SPW;

    // h exchange: [buf][sample(16) x 64 units] bf16, 16B blocks XOR-swizzled
    // by (sample&7) so the per-sample b128 column read is conflict-free.
    __shared__ __align__(16) ushort hb[2][16 * 64];          // 4 KB
    // staged inputs: [buf][step][sample][32 dim-slots] bf16; slot q*8+j holds
    // original dim q*5+j for j<5, else ZERO pad (stage16 writes all slots).
    __shared__ __align__(16) ushort xb[2][GS][16][32];       // 16 KB

    // ---- B fragments (weights), built once; k-map: k = c*32 + lg*8 + e ----
    const int u = 16 * w + l15;    // this wave's output unit
    bf16x8 Bxr, Bxz, Bxn, Bhr0, Bhr1, Bhz0, Bhz1, Bhn0, Bhn1;
#pragma unroll
    for (int e = 0; e < 8; ++e) {
        const int d = lg * 5 + e;            // x k-map: slot lg*8+e <-> dim lg*5+e (e<5)
        Bxr[e] = (e < 5) ? f2bf(Wi[d * G3 + u])       : (short)0;
        Bxz[e] = (e < 5) ? f2bf(Wi[d * G3 + 64 + u])  : (short)0;
        Bxn[e] = (e < 5) ? f2bf(Wi[d * G3 + 128 + u]) : (short)0;
        const int k0 = lg * 8 + e, k1 = 32 + lg * 8 + e;
        Bhr0[e] = f2bf(Wh[k0 * G3 + u]);       Bhr1[e] = f2bf(Wh[k1 * G3 + u]);
        Bhz0[e] = f2bf(Wh[k0 * G3 + 64 + u]);  Bhz1[e] = f2bf(Wh[k1 * G3 + 64 + u]);
        Bhn0[e] = f2bf(Wh[k0 * G3 + 128 + u]); Bhn1[e] = f2bf(Wh[k1 * G3 + 128 + u]);
    }
    bf16x8 Bmv0 = {}, Bmv1 = {};   // waves 0,1: mv cols 0..15 / 16..19(+pad)
    if (w < 2) {
        const int c = 16 * w + l15;
#pragma unroll
        for (int e = 0; e < 8; ++e) {
            const int k0 = lg * 8 + e, k1 = 32 + lg * 8 + e;
            float v0 = 0.f, v1 = 0.f;
            if (c < 10)      { v0 = Wmu[k0 * NS + c];        v1 = Wmu[k1 * NS + c]; }
            else if (c < 20) { v0 = Wvar[k0 * NS + (c - 10)]; v1 = Wvar[k1 * NS + (c - 10)]; }
            Bmv0[e] = f2bf(v0); Bmv1[e] = f2bf(v1);
        }
    }
    const float br  = bi[u] + bh[u];
    const float bz  = bi[64 + u] + bh[64 + u];
    const float bnx = bi[128 + u];
    const float bnh = bh[128 + u];

    // ---- LDS address precompute ----
    // read chunk c: sample=l15, physical 16B block = (c*4+lg) ^ (l15&7)
    const int hro0 = l15 * 64 + (((0 + lg) ^ (l15 & 7)) << 3);
    const int hro1 = l15 * 64 + (((4 + lg) ^ (l15 & 7)) << 3);
    // write h: sample s = 4*lg+r, unit u: pos = ((u>>3)^(s&7))*8 + (u&7)
    int hwo[4];
#pragma unroll
    for (int r = 0; r < 4; ++r) {
        const int s = 4 * lg + r;
        hwo[r] = s * 64 + ((((u >> 3)) ^ (s & 7)) << 3) + (u & 7);
    }

    // ---- input staging roles: thread = (sample ss, step st_t, half sh) ----
    const int ss   = tid >> 4;       // sample 0..15
    const int ii   = tid & 15;
    const int st_t = ii >> 1;        // step-in-group 0..7
    const int sh   = ii & 1;         // 0 = y dims 0..9, 1 = x dims 10..19
    const float* src_base = sh ? (Xh + (size_t)(n0 + ss) * TT * NS)
                               : (Yi + (size_t)(n0 + ss) * TT * NO);

    // ---- prologue: zero h buffers, stage group 0 ----
    {
        ushort* hf = (ushort*)hb;
        for (int i = tid; i < 2 * 16 * 64; i += 256) hf[i] = 0;
        const float* p = src_base + (size_t)st_t * 10;
        const float2 L0 = *(const float2*)(p);
        const float2 L1 = *(const float2*)(p + 2);
        const float2 L2 = *(const float2*)(p + 4);
        const float2 L3 = *(const float2*)(p + 6);
        const float2 L4 = *(const float2*)(p + 8);
        stage16(&xb[0][st_t][ss][sh * 16], L0, L1, L2, L3, L4);
        sync_lds();
    }

    float hreg[4] = {0.f, 0.f, 0.f, 0.f};   // h for (unit u, samples 4*lg+r)

#pragma unroll 1
    for (int g = 0; g < NG; ++g) {
        const int bq = g & 1;
        // prefetch next group's 10 floats; cvt+write at st==7 (R0 pattern)
        float2 L0, L1, L2, L3, L4;
        const bool do_ld = (g + 1 < NG);
        if (do_ld) {
            const float* p = src_base + (size_t)((g + 1) * GS + st_t) * 10;
            L0 = *(const float2*)(p);     L1 = *(const float2*)(p + 2);
            L2 = *(const float2*)(p + 4); L3 = *(const float2*)(p + 6);
            L4 = *(const float2*)(p + 8);
        }

#pragma unroll
        for (int st = 0; st < GS; ++st) {
            const int p = st & 1;        // h parity: t = 8g+st, 8g even
            const int t = 8 * g + st;
            // A-fragments (issue all 3 reads up front)
            const bf16x8 xa = *(const bf16x8*)&xb[bq][st][l15][lg * 8];
            const bf16x8 h0 = *(const bf16x8*)((const ushort*)hb[p] + hro0);
            const bf16x8 h1 = *(const bf16x8*)((const ushort*)hb[p] + hro1);

            f32x4 ar = {br, br, br, br}, az = {bz, bz, bz, bz};
            f32x4 ax = {bnx, bnx, bnx, bnx}, ah = {bnh, bnh, bnh, bnh};
            // x-chunk MFMAs can run while h reads are still in flight
            ar = MFMA16(xa, Bxr, ar, 0, 0, 0);
            az = MFMA16(xa, Bxz, az, 0, 0, 0);
            ax = MFMA16(xa, Bxn, ax, 0, 0, 0);
            ar = MFMA16(h0, Bhr0, ar, 0, 0, 0);
            az = MFMA16(h0, Bhz0, az, 0, 0, 0);
            ah = MFMA16(h0, Bhn0, ah, 0, 0, 0);
            ar = MFMA16(h1, Bhr1, ar, 0, 0, 0);
            az = MFMA16(h1, Bhz1, az, 0, 0, 0);
            ah = MFMA16(h1, Bhn1, ah, 0, 0, 0);
            if (w < 2) {   // mv from h_{t-1} -> output t-1 (fire-and-forget)
                f32x4 amv = {0.f, 0.f, 0.f, 0.f};
                amv = MFMA16(h0, Bmv0, amv, 0, 0, 0);
                amv = MFMA16(h1, Bmv1, amv, 0, 0, 0);
                if (t > 0) {
#pragma unroll
                    for (int r = 0; r < 4; ++r) {
                        const size_t smp = (size_t)(n0 + 4 * lg + r);
                        if (w == 0)
                            mv_out[(smp * TT + (t - 1)) * DIN + l15] = amv[r];
                        else if (l15 < 4)
                            mv_out[(smp * TT + (t - 1)) * DIN + 16 + l15] = amv[r];
                    }
                }
            }
            // nonlinearity (f32, identical numerics to the verified kernel)
#pragma unroll
            for (int r = 0; r < 4; ++r) {
                const float rr  = rcpf(1.f + __expf(-ar[r]));
                const float zz  = rcpf(1.f + __expf(-az[r]));
                const float pre = fmaf(rr, ah[r], ax[r]);
                const float e2  = __expf(2.f * pre);       // inf-safe
                const float nn  = 1.f - 2.f * rcpf(e2 + 1.f);
                hreg[r] = fmaf(zz, hreg[r] - nn, nn);
            }
            const unsigned pk01 = cvt_pk_bf16(hreg[0], hreg[1]);
            const unsigned pk23 = cvt_pk_bf16(hreg[2], hreg[3]);
            ushort* hw = (ushort*)hb[p ^ 1];
            hw[hwo[0]] = (ushort)pk01;
            hw[hwo[1]] = (ushort)(pk01 >> 16);
            hw[hwo[2]] = (ushort)pk23;
            hw[hwo[3]] = (ushort)(pk23 >> 16);
            // stage next group's inputs just before the group's last barrier
            if (st == GS - 1 && do_ld)
                stage16(&xb[bq ^ 1][st_t][ss][sh * 16], L0, L1, L2, L3, L4);
            sync_lds();
        }
    }

    // epilogue: mv for t=999 from h_999 (written to hb[0] by the last step)
    if (w < 2) {
        const bf16x8 h0 = *(const bf16x8*)((const ushort*)hb[0] + hro0);
        const bf16x8 h1 = *(const bf16x8*)((const ushort*)hb[0] + hro1);
        f32x4 amv = {0.f, 0.f, 0.f, 0.f};
        amv = MFMA16(h0, Bmv0, amv, 0, 0, 0);
        amv = MFMA16(h1, Bmv1, amv, 0, 0, 0);
#pragma unroll
        for (int r = 0; r < 4; ++r) {
            const size_t smp = (size_t)(n0 + 4 * lg + r);
            if (w == 0)
                mv_out[(smp * TT + (TT - 1)) * DIN + l15] = amv[r];
            else if (l15 < 4)
                mv_out[(smp * TT + (TT - 1)) * DIN + 16 + l15] = amv[r];
        }
    }
}

// ---------------- d_out init: the constant term ----------------------------
__global__ void init_out(float* out) {
    // -0.5*NO*T*log(2pi) / (T*NO) = -0.5*log(2pi)
    out[0] = -0.918938533204672742f;
}

// ---------------- Phase 2: per-(n,t) Gaussian log-lik (unchanged) ----------
__global__ __launch_bounds__(256)
void lik_phase2(const float* __restrict__ Yi, const float* __restrict__ Cw,
                const float* __restrict__ Hm, const float* __restrict__ mu_w,
                const float* __restrict__ b_mu, const float* __restrict__ b_var,
                const float* __restrict__ mv_in, float* __restrict__ out) {
    __shared__ float sH[NO * NS];
    __shared__ float smw[NO], sbm[NS], sbv[NS];
    __shared__ float ssum[4];
    const int tid = threadIdx.x;
    if (tid < NO * NS) sH[tid] = Hm[tid];
    if (tid < NO) smw[tid] = mu_w[tid];
    if (tid < NS) { sbm[tid] = b_mu[tid]; sbv[tid] = b_var[tid]; }
    __syncthreads();

    const int gid = blockIdx.x * 256 + tid;   // 0 .. BN*TT-1
    float contrib = 0.0f;
    if (gid < BN * TT) {
        const int n = gid / TT;
        const float* mv = mv_in + (size_t)gid * DIN;
        float mu[NS], va[NS];
#pragma unroll
        for (int i = 0; i < NS; ++i) {
            mu[i] = mv[i] + sbm[i];
            float x = mv[NS + i] + sbv[i];
            va[i] = (x > 0.0f) ? (x + log1pf(__expf(-x))) : log1pf(__expf(x));
        }
        const float* y = Yi + (size_t)gid * NO;
        float e[NO];
#pragma unroll
        for (int i = 0; i < NO; ++i) {
            float m = smw[i];
#pragma unroll
            for (int j = 0; j < NS; ++j) m = fmaf(sH[i * NS + j], mu[j], m);
            e[i] = y[i] - m;
        }
        // M = H diag(va) H^T + Cw (lower triangle only)
        float M[NO][NO];
        const float* cw = Cw + (size_t)n * NO * NO;
#pragma unroll
        for (int i = 0; i < NO; ++i)
#pragma unroll
            for (int j = 0; j <= i; ++j) M[i][j] = cw[i * NO + j];
#pragma unroll
        for (int l = 0; l < NS; ++l) {
            float vl = va[l];
            float hv[NO];
#pragma unroll
            for (int i = 0; i < NO; ++i) hv[i] = sH[i * NS + l];
#pragma unroll
            for (int i = 0; i < NO; ++i) {
                float hvi = hv[i] * vl;
#pragma unroll
                for (int j = 0; j <= i; ++j) M[i][j] = fmaf(hvi, hv[j], M[i][j]);
            }
        }
        // in-place Cholesky (lower); fast rsqrt/rcp (error ~1ulp, harmless
        // vs the 3.1e-2 threshold on an averaged scalar)
        float logdet = 0.0f;
        float drs[NO];
#pragma unroll
        for (int j = 0; j < NO; ++j) {
            float d = M[j][j];
#pragma unroll
            for (int k = 0; k < j; ++k) d = fmaf(-M[j][k], M[j][k], d);
            logdet += __logf(d);
            float rs = __frsqrt_rn(d);
            drs[j] = rs;
            M[j][j] = d * rs;
#pragma unroll
            for (int i = j + 1; i < NO; ++i) {
                float v = M[i][j];
#pragma unroll
                for (int k = 0; k < j; ++k) v = fmaf(-M[i][k], M[j][k], v);
                M[i][j] = v * rs;
            }
        }
        // quad = || L^-1 e ||^2 (forward solve)
        float wv[NO];
        float quad = 0.0f;
#pragma unroll
        for (int i = 0; i < NO; ++i) {
            float v = e[i];
#pragma unroll
            for (int k = 0; k < i; ++k) v = fmaf(-M[i][k], wv[k], v);
            wv[i] = v * drs[i] * rcpf(M[i][i] * drs[i]);
            quad = fmaf(wv[i], wv[i], quad);
        }
        const float SCALE = 0.5f / ((float)BN * (float)TT * (float)NO);
        contrib = -(logdet + quad) * SCALE;
    }

#pragma unroll
    for (int off = 32; off > 0; off >>= 1) contrib += __shfl_down(contrib, off);
    if ((tid & 63) == 0) ssum[tid >> 6] = contrib;
    __syncthreads();
    if (tid == 0) {
        float s = ssum[0] + ssum[1] + ssum[2] + ssum[3];
        atomicAdd(out, s);
    }
}

// ---------------- launch ---------------------------------------------------
extern "C" void kernel_launch(void* const* d_in, const int* in_sizes, int n_in,
                              void* d_out, int out_size, void* d_ws, size_t ws_size,
                              hipStream_t stream) {
    const float* Yi    = (const float*)d_in[0];
    const float* Xh    = (const float*)d_in[1];
    const float* Cw    = (const float*)d_in[2];
    const float* Hm    = (const float*)d_in[3];
    const float* mu_w  = (const float*)d_in[4];
    const float* Wi    = (const float*)d_in[5];
    const float* Wh    = (const float*)d_in[6];
    const float* bi    = (const float*)d_in[7];
    const float* bh    = (const float*)d_in[8];
    const float* W_mu  = (const float*)d_in[9];
    const float* b_mu  = (const float*)d_in[10];
    const float* W_var = (const float*)d_in[11];
    const float* b_var = (const float*)d_in[12];
    float* out = (float*)d_out;
    float* mv  = (float*)d_ws;   // [BN*TT*DIN] floats = 20.48 MB

    init_out<<<1, 1, 0, stream>>>(out);
    gru_mfma<<<dim3(NBLK), dim3(256), 0, stream>>>(Yi, Xh, Wi, Wh, bi, bh,
                                                   W_mu, W_var, mv);
    lik_phase2<<<dim3((BN * TT + 255) / 256), dim3(256), 0, stream>>>(
        Yi, Cw, Hm, mu_w, b_mu, b_var, mv, out);
}